// Round 8
// baseline (10500.790 us; speedup 1.0000x reference)
//
#include <hip/hip_runtime.h>
#include <hip/hip_bf16.h>

// RSSM scan: B=512, T=64, STOCH=32, DETER=512, HIDDEN=512, ACT=12, EMBED=1024
// out per (b,t): [ostoch32, om32, ostd32, pstoch32, pm32, ps32, deter512] = 704 f32
// Strategy: 32 blocks (4/XCD), each owns 16 batch rows for all 64 steps.
// Weights in nt-major MFMA-fragment layout (round-4: proven compulsory-only L2
// fetch). K-loops software-pipelined with sched_barrier(0)-pinned load groups
// so the compiler cannot sink the prefetch (rounds 5-7: VGPR=64 proved it did).

typedef __attribute__((ext_vector_type(8))) short bf16x8;
typedef __attribute__((ext_vector_type(4))) float f32x4;

static __device__ __forceinline__ short f2b(float x){
  __hip_bfloat16 h = __float2bfloat16(x);
  return *reinterpret_cast<short*>(&h);
}
static __device__ __forceinline__ float b2f(short s){
  __hip_bfloat16 h = *reinterpret_cast<__hip_bfloat16*>(&s);
  return __bfloat162float(h);
}
static __device__ __forceinline__ float softplusf_(float x){
  return (x > 20.f) ? x : log1pf(expf(x));
}
static __device__ __forceinline__ float sigm(float x){ return 1.f/(1.f+expf(-x)); }
#define SBAR() __builtin_amdgcn_sched_barrier(0)

// ---------------- weight convert (one-time): nt-MAJOR fragment layouts ------
// value(nt,ks,l,e) = W[k][n], k=ks*32+(l>>4)*8+e, n=nt*16+(l&15)
// linear = ((nt*NKS + ks)*64 + l)*8 + e
__global__ __launch_bounds__(256) void k_wt(
    const float* __restrict__ wi, const float* __restrict__ wg,
    const float* __restrict__ wo, const float* __restrict__ wst,
    const float* __restrict__ wou,
    short* __restrict__ WinT, short* __restrict__ WgruT,
    short* __restrict__ WobsT, short* __restrict__ WostatT,
    short* __restrict__ WoutT){
  int i = blockIdx.x*256 + threadIdx.x;
  if(i < 32768){ // w_in: NT=32, NKS=2 (real K=44)
    int e=i&7, l=(i>>3)&63, f=i>>9; int ks=f&1, nt=f>>1;
    int k=ks*32+((l>>4))*8+e, n=nt*16+(l&15);
    WinT[i] = (k<44)? f2b(wi[k*512+n]) : (short)0;
    return;
  }
  i -= 32768;
  if(i < 1572864){ // w_gru: NT=96, NKS=32
    int e=i&7, l=(i>>3)&63, f=i>>9; int ks=f&31, nt=f>>5;
    int k=ks*32+((l>>4))*8+e, n=nt*16+(l&15);
    WgruT[i] = f2b(wg[k*1536+n]);
    return;
  }
  i -= 1572864;
  if(i < 786432){ // w_obs: NT=32, NKS=48
    int e=i&7, l=(i>>3)&63, f=i>>9; int ks=f%48, nt=f/48;
    int k=ks*32+((l>>4))*8+e, n=nt*16+(l&15);
    WobsT[i] = f2b(wo[k*512+n]);
    return;
  }
  i -= 786432;
  if(i < 32768){ // w_ostat: NT=4, NKS=16
    int e=i&7, l=(i>>3)&63, f=i>>9; int ks=f&15, nt=f>>4;
    int k=ks*32+((l>>4))*8+e, n=nt*16+(l&15);
    WostatT[i] = f2b(wst[k*64+n]);
    return;
  }
  i -= 32768;
  { int n=i>>9, k=i&511; WoutT[i] = f2b(wou[k*512+n]); } // w_out row-major [n][k]
}

// ---------------- init: deter0 = tanh(W_init); stoch0 = img_mean(deter0) -----
__global__ __launch_bounds__(512) void k_init(const float* __restrict__ W_init,
    const float* __restrict__ w_out, const float* __restrict__ og, const float* __restrict__ ob,
    const float* __restrict__ w_ims, const float* __restrict__ b_ims,
    float* __restrict__ deter0, float* __restrict__ stoch0){
  __shared__ float d0[512]; __shared__ float red[512]; __shared__ float x2[512];
  int tid = threadIdx.x;
  float d = tanhf(W_init[tid]); d0[tid] = d; deter0[tid] = d; __syncthreads();
  float s = 0.f;
  for(int k=0;k<512;k++) s += d0[k]*w_out[k*512+tid];
  red[tid] = s; __syncthreads();
  for(int ss=256; ss>0; ss>>=1){ if(tid<ss) red[tid]+=red[tid+ss]; __syncthreads(); }
  float sum = red[0]; __syncthreads();
  red[tid] = s*s; __syncthreads();
  for(int ss=256; ss>0; ss>>=1){ if(tid<ss) red[tid]+=red[tid+ss]; __syncthreads(); }
  float sq = red[0];
  float mu = sum/512.f, var = sq/512.f - mu*mu;
  float rstd = rsqrtf(var + 1e-3f);
  float xn = (s-mu)*rstd*og[tid] + ob[tid];
  float xs = xn*sigm(xn);
  x2[tid] = xs; __syncthreads();
  if(tid < 32){
    float acc = b_ims[tid];
    for(int k=0;k<512;k++) acc += x2[k]*w_ims[k*64+tid];
    stoch0[tid] = acc;
  }
}

// ---------------- the scan: 32 blocks x 1024 threads ------------------------
__global__ __launch_bounds__(1024, 4) void k_scan(
    const float* __restrict__ embed, const float* __restrict__ action,
    const float* __restrict__ isf, const float* __restrict__ eps_post,
    const short* __restrict__ WinT, const float* __restrict__ ig, const float* __restrict__ ib,
    const short* __restrict__ WgruT, const float* __restrict__ gg, const float* __restrict__ gb,
    const short* __restrict__ WobsT, const float* __restrict__ og, const float* __restrict__ ob,
    const short* __restrict__ WostatT, const float* __restrict__ b_ostat,
    const float* __restrict__ deter0, const float* __restrict__ stoch0,
    float* __restrict__ out)
{
  __shared__ __align__(16) short RB[16*1032];   // xd bf16[16][1032] / embB
  __shared__ __align__(16) short PB[16*1544];   // parts bf16[16][1544] / xoF f32[16][520]
  __shared__ float deterS[16][516];
  __shared__ short dB[16][520];
  __shared__ short xrow[16][72];
  __shared__ float stochS[16][32];
  __shared__ float sol[16][64];
  __shared__ float sumA[16], sqA[16], sumB[16], sqB[16], sumC[16], sqC[16];
  __shared__ float fr[16];
  __shared__ float d0s[512]; __shared__ float s0s[32];

  const int g = blockIdx.x, tid = threadIdx.x;
  const int w = tid>>6, lane = tid&63;
  const int col0 = lane&15, rg4 = (lane>>4)*4;
  const int afo = (lane>>4)*8;
  float* xoF = (float*)PB;

  // ---- init state ----
  if(tid < 512) d0s[tid] = deter0[tid];
  if(tid < 32)  s0s[tid] = stoch0[tid];
  __syncthreads();
  { int r = tid>>6, kb = (tid&63)*8;
    #pragma unroll
    for(int i=0;i<8;i++) deterS[r][kb+i] = d0s[kb+i]; }
  if(tid < 512){ int r=tid>>5, c=tid&31; stochS[r][c] = s0s[c]; }
  __syncthreads();

  for(int t=0; t<64; t++){
    // ---- S0a: is_first + zero LN-stat buffers ----
    if(tid < 16){
      fr[tid] = isf[(g*16+tid)*64 + t];
      sumA[tid]=0.f; sqA[tid]=0.f; sumB[tid]=0.f; sqB[tid]=0.f; sumC[tid]=0.f; sqC[tid]=0.f;
    }
    __syncthreads();
    // ---- S0b: mask stoch/action -> xrow; mask deter -> deterS + xd[512:1024] ----
    if(tid < 512){
      int r = tid>>5, c = tid&31; float f = fr[r];
      float sm = stochS[r][c]*(1.f-f) + s0s[c]*f;
      xrow[r][c] = f2b(sm);
      if(c < 12){
        float av = action[((size_t)(g*16+r)*64+t)*12 + c]*(1.f-f);
        xrow[r][32+c] = f2b(av);
      }
      if(c >= 12) xrow[r][32+c] = 0;
    }
    { int r = tid>>6, kb = (tid&63)*8; float f = fr[r];
      #pragma unroll
      for(int i=0;i<8;i++){
        int k = kb+i;
        float dm = deterS[r][k]*(1.f-f) + d0s[k]*f;
        deterS[r][k] = dm;
        RB[r*1032 + 512 + k] = f2b(dm);
      } }
    __syncthreads();
    // ---- S1: x_pre = xrow @ w_in -> xd[0:512] + statsA ----
    {
      f32x4 acc[2] = {};
      #pragma unroll
      for(int ks=0; ks<2; ks++){
        bf16x8 a = *(const bf16x8*)&xrow[col0][ks*32 + afo];
        #pragma unroll
        for(int j=0;j<2;j++){
          int nt = w*2+j;
          bf16x8 b = *(const bf16x8*)&WinT[((nt*2 + ks)*64 + lane)*8];
          acc[j] = __builtin_amdgcn_mfma_f32_16x16x32_bf16(a,b,acc[j],0,0,0);
        }
      }
      float s[4]={0,0,0,0}, q[4]={0,0,0,0};
      #pragma unroll
      for(int j=0;j<2;j++){
        int col = (w*2+j)*16 + col0;
        #pragma unroll
        for(int r=0;r<4;r++){
          float v = acc[j][r];
          RB[(rg4+r)*1032 + col] = f2b(v);
          s[r]+=v; q[r]+=v*v;
        }
      }
      #pragma unroll
      for(int r=0;r<4;r++){
        #pragma unroll
        for(int m=1;m<16;m<<=1){ s[r]+=__shfl_xor(s[r],m); q[r]+=__shfl_xor(q[r],m); }
      }
      if(col0==0){
        #pragma unroll
        for(int r=0;r<4;r++){ atomicAdd(&sumA[rg4+r], s[r]); atomicAdd(&sqA[rg4+r], q[r]); }
      }
    }
    __syncthreads();
    // ---- S2: LN+silu x in place ----
    {
      int r = tid>>6, kb = tid&63;
      float mu = sumA[r]/512.f, var = sqA[r]/512.f - mu*mu;
      float rstd = rsqrtf(var + 1e-3f);
      #pragma unroll
      for(int i=0;i<8;i++){
        int k = kb + i*64;
        float v = b2f(RB[r*1032 + k]);
        float xn = (v-mu)*rstd*ig[k] + ib[k];
        RB[r*1032 + k] = f2b(xn*sigm(xn));
      }
    }
    __syncthreads();
    // ---- S3: parts = xd @ w_gru (nt-major streams, sched_barrier-pinned dbuf)
    float4 er[4];  // embed row, loaded in epilogue, consumed at S4
    {
      f32x4 acc[6] = {};
      const short* Wp = WgruT + (size_t)(w*6)*16384 + (size_t)lane*8; // +j*16384 +ks*512
      const short* xdA = &RB[col0*1032 + afo];
      bf16x8 b0[6], b1[6];
      #pragma unroll
      for(int j=0;j<6;j++) b0[j] = *(const bf16x8*)(Wp + j*16384);
      #pragma unroll
      for(int j=0;j<6;j++) b1[j] = *(const bf16x8*)(Wp + j*16384 + 512);
      SBAR();
      for(int ks=0; ks<32; ks+=2){
        bf16x8 a0 = *(const bf16x8*)(xdA + ks*32);
        #pragma unroll
        for(int j=0;j<6;j++) acc[j] = __builtin_amdgcn_mfma_f32_16x16x32_bf16(a0,b0[j],acc[j],0,0,0);
        SBAR();
        if(ks+2 < 32){
          #pragma unroll
          for(int j=0;j<6;j++) b0[j] = *(const bf16x8*)(Wp + j*16384 + (ks+2)*512);
        }
        SBAR();
        bf16x8 a1 = *(const bf16x8*)(xdA + ks*32 + 32);
        #pragma unroll
        for(int j=0;j<6;j++) acc[j] = __builtin_amdgcn_mfma_f32_16x16x32_bf16(a1,b1[j],acc[j],0,0,0);
        SBAR();
        if(ks+3 < 32){
          #pragma unroll
          for(int j=0;j<6;j++) b1[j] = *(const bf16x8*)(Wp + j*16384 + (ks+3)*512);
        }
        SBAR();
      }
      // issue embed loads now (HBM latency hides under stats + barrier + S4)
      { const float4* ep = (const float4*)&embed[((size_t)(g*16+w)*64+t)*1024 + lane*16];
        er[0]=ep[0]; er[1]=ep[1]; er[2]=ep[2]; er[3]=ep[3]; }
      float s[4]={0,0,0,0}, q[4]={0,0,0,0};
      #pragma unroll
      for(int j=0;j<6;j++){
        int col = (w*6+j)*16 + col0;
        #pragma unroll
        for(int r=0;r<4;r++){
          float v = acc[j][r];
          PB[(rg4+r)*1544 + col] = f2b(v);
          s[r]+=v; q[r]+=v*v;
        }
      }
      #pragma unroll
      for(int r=0;r<4;r++){
        #pragma unroll
        for(int m=1;m<16;m<<=1){ s[r]+=__shfl_xor(s[r],m); q[r]+=__shfl_xor(q[r],m); }
      }
      if(col0==0){
        #pragma unroll
        for(int r=0;r<4;r++){ atomicAdd(&sumB[rg4+r], s[r]); atomicAdd(&sqB[rg4+r], q[r]); }
      }
    }
    __syncthreads();
    // ---- S4: embB write (from er) + gates LN(1536)+GRU -> deterS, dB, out ----
    {
      bf16x8 v0, v1;
      v0[0]=f2b(er[0].x); v0[1]=f2b(er[0].y); v0[2]=f2b(er[0].z); v0[3]=f2b(er[0].w);
      v0[4]=f2b(er[1].x); v0[5]=f2b(er[1].y); v0[6]=f2b(er[1].z); v0[7]=f2b(er[1].w);
      v1[0]=f2b(er[2].x); v1[1]=f2b(er[2].y); v1[2]=f2b(er[2].z); v1[3]=f2b(er[2].w);
      v1[4]=f2b(er[3].x); v1[5]=f2b(er[3].y); v1[6]=f2b(er[3].z); v1[7]=f2b(er[3].w);
      *reinterpret_cast<bf16x8*>(&RB[w*1032 + lane*16])     = v0;
      *reinterpret_cast<bf16x8*>(&RB[w*1032 + lane*16 + 8]) = v1;
    }
    {
      int r = tid>>6, jb = tid&63;
      float mu = sumB[r]/1536.f, var = sqB[r]/1536.f - mu*mu;
      float rstd = rsqrtf(var + 1e-3f);
      size_t obase = (size_t)(g*16+r)*45056 + (size_t)t*704 + 192;
      #pragma unroll
      for(int i=0;i<8;i++){
        int j = jb + i*64;
        float xr = (b2f(PB[r*1544 + j      ])-mu)*rstd*gg[j]      + gb[j];
        float xc = (b2f(PB[r*1544 + 512 + j])-mu)*rstd*gg[512+j]  + gb[512+j];
        float xu = (b2f(PB[r*1544 + 1024+ j])-mu)*rstd*gg[1024+j] + gb[1024+j];
        float rr = sigm(xr);
        float cc = tanhf(rr*xc);
        float uu = sigm(xu-1.f);
        float dp = deterS[r][j];
        float dn = uu*cc + (1.f-uu)*dp;
        deterS[r][j] = dn;
        dB[r][j] = f2b(dn);
        out[obase + j] = dn;
      }
    }
    __syncthreads();
    // ---- S6: xo_pre = [deter_n | embed] @ w_obs (4-deep pinned pipeline) ----
    {
      f32x4 acc[2] = {};
      const short* Wo = WobsT + (size_t)(w*2)*24576 + (size_t)lane*8; // +j*24576 +ks*512
      bf16x8 c0[2], c1[2], c2[2], c3[2];
      #pragma unroll
      for(int j=0;j<2;j++){
        c0[j] = *(const bf16x8*)(Wo + j*24576);
        c1[j] = *(const bf16x8*)(Wo + j*24576 + 512);
        c2[j] = *(const bf16x8*)(Wo + j*24576 + 1024);
        c3[j] = *(const bf16x8*)(Wo + j*24576 + 1536);
      }
      SBAR();
      for(int ks=0; ks<48; ks+=4){
        // phase 0
        { int kk = ks;
          const short* ap = (kk<16) ? &dB[col0][kk*32 + afo] : &RB[col0*1032 + (kk-16)*32 + afo];
          bf16x8 a = *(const bf16x8*)ap;
          acc[0] = __builtin_amdgcn_mfma_f32_16x16x32_bf16(a,c0[0],acc[0],0,0,0);
          acc[1] = __builtin_amdgcn_mfma_f32_16x16x32_bf16(a,c0[1],acc[1],0,0,0);
          SBAR();
          if(kk+4 < 48){
            c0[0] = *(const bf16x8*)(Wo + (kk+4)*512);
            c0[1] = *(const bf16x8*)(Wo + 24576 + (kk+4)*512);
          }
          SBAR();
        }
        // phase 1
        { int kk = ks+1;
          const short* ap = (kk<16) ? &dB[col0][kk*32 + afo] : &RB[col0*1032 + (kk-16)*32 + afo];
          bf16x8 a = *(const bf16x8*)ap;
          acc[0] = __builtin_amdgcn_mfma_f32_16x16x32_bf16(a,c1[0],acc[0],0,0,0);
          acc[1] = __builtin_amdgcn_mfma_f32_16x16x32_bf16(a,c1[1],acc[1],0,0,0);
          SBAR();
          if(kk+4 < 48){
            c1[0] = *(const bf16x8*)(Wo + (kk+4)*512);
            c1[1] = *(const bf16x8*)(Wo + 24576 + (kk+4)*512);
          }
          SBAR();
        }
        // phase 2
        { int kk = ks+2;
          const short* ap = (kk<16) ? &dB[col0][kk*32 + afo] : &RB[col0*1032 + (kk-16)*32 + afo];
          bf16x8 a = *(const bf16x8*)ap;
          acc[0] = __builtin_amdgcn_mfma_f32_16x16x32_bf16(a,c2[0],acc[0],0,0,0);
          acc[1] = __builtin_amdgcn_mfma_f32_16x16x32_bf16(a,c2[1],acc[1],0,0,0);
          SBAR();
          if(kk+4 < 48){
            c2[0] = *(const bf16x8*)(Wo + (kk+4)*512);
            c2[1] = *(const bf16x8*)(Wo + 24576 + (kk+4)*512);
          }
          SBAR();
        }
        // phase 3
        { int kk = ks+3;
          const short* ap = (kk<16) ? &dB[col0][kk*32 + afo] : &RB[col0*1032 + (kk-16)*32 + afo];
          bf16x8 a = *(const bf16x8*)ap;
          acc[0] = __builtin_amdgcn_mfma_f32_16x16x32_bf16(a,c3[0],acc[0],0,0,0);
          acc[1] = __builtin_amdgcn_mfma_f32_16x16x32_bf16(a,c3[1],acc[1],0,0,0);
          SBAR();
          if(kk+4 < 48){
            c3[0] = *(const bf16x8*)(Wo + (kk+4)*512);
            c3[1] = *(const bf16x8*)(Wo + 24576 + (kk+4)*512);
          }
          SBAR();
        }
      }
      __syncthreads();  // embB/parts reads done before xoF (PB) overwrite
      float s[4]={0,0,0,0}, q[4]={0,0,0,0};
      #pragma unroll
      for(int j=0;j<2;j++){
        int col = (w*2+j)*16 + col0;
        #pragma unroll
        for(int r=0;r<4;r++){
          float v = acc[j][r];
          xoF[(rg4+r)*520 + col] = v;
          s[r]+=v; q[r]+=v*v;
        }
      }
      #pragma unroll
      for(int r=0;r<4;r++){
        #pragma unroll
        for(int m=1;m<16;m<<=1){ s[r]+=__shfl_xor(s[r],m); q[r]+=__shfl_xor(q[r],m); }
      }
      if(col0==0){
        #pragma unroll
        for(int r=0;r<4;r++){ atomicAdd(&sumC[rg4+r], s[r]); atomicAdd(&sqC[rg4+r], q[r]); }
      }
    }
    __syncthreads();
    // ---- S7: LN+silu xo -> dB ----
    {
      int r = tid>>6, kb = tid&63;
      float mu = sumC[r]/512.f, var = sqC[r]/512.f - mu*mu;
      float rstd = rsqrtf(var + 1e-3f);
      #pragma unroll
      for(int i=0;i<8;i++){
        int k = kb + i*64;
        float v = xoF[r*520 + k];
        float xn = (v-mu)*rstd*og[k] + ob[k];
        dB[r][k] = f2b(xn*sigm(xn));
      }
    }
    __syncthreads();
    // ---- S8: so = xo @ w_ostat (waves 0..3, pinned dbuf) ----
    if(w < 4){
      f32x4 acc = {};
      const short* Wl = WostatT + (size_t)w*8192 + (size_t)lane*8;  // +ks*512
      bf16x8 b0 = *(const bf16x8*)(Wl);
      bf16x8 b1 = *(const bf16x8*)(Wl + 512);
      SBAR();
      for(int ks=0; ks<16; ks+=2){
        bf16x8 a0 = *(const bf16x8*)&dB[col0][ks*32 + afo];
        acc = __builtin_amdgcn_mfma_f32_16x16x32_bf16(a0,b0,acc,0,0,0);
        SBAR();
        if(ks+2<16) b0 = *(const bf16x8*)(Wl + (ks+2)*512);
        SBAR();
        bf16x8 a1 = *(const bf16x8*)&dB[col0][(ks+1)*32 + afo];
        acc = __builtin_amdgcn_mfma_f32_16x16x32_bf16(a1,b1,acc,0,0,0);
        SBAR();
        if(ks+3<16) b1 = *(const bf16x8*)(Wl + (ks+3)*512);
        SBAR();
      }
      #pragma unroll
      for(int r=0;r<4;r++) sol[rg4+r][w*16+col0] = acc[r];
    }
    __syncthreads();
    // ---- S9: om/ostd/ostoch, write out, update stoch carry ----
    if(tid < 512){
      int r = tid>>5, c = tid&31;
      float om  = sol[r][c]    + b_ostat[c];
      float spi = sol[r][32+c] + b_ostat[32+c];
      float osd = softplusf_(spi) + 0.1f;
      float eo  = eps_post[((size_t)(g*16+r)*64+t)*32 + c];
      float ost = om + osd*eo;
      size_t base = (size_t)(g*16+r)*45056 + (size_t)t*704;
      out[base+c] = ost; out[base+32+c] = om; out[base+64+c] = osd;
      stochS[r][c] = ost;
    }
    __syncthreads();
  }
}

// ---------------- deferred img-branch GEMM: x2pre = deter_all @ w_out --------
__global__ __launch_bounds__(256) void k_img(const float* __restrict__ outp,
    const short* __restrict__ WoT, short* __restrict__ x2pre){
  __shared__ __align__(16) short As[128][72];
  __shared__ __align__(16) short Bs[128][72];
  int tid = threadIdx.x, lane = tid&63, wid = tid>>6;
  int wm = (wid>>1)*64, wn = (wid&1)*64;
  int mP = blockIdx.x*128, nP = blockIdx.y*128;
  f32x4 acc[4][4] = {};
  for(int kt=0; kt<512; kt+=64){
    #pragma unroll
    for(int c=0;c<4;c++){
      int idx = tid + c*256; int r = idx>>3, kc = (idx&7)*8;
      const float* src = &outp[(size_t)(mP+r)*704 + 192 + kt + kc];
      float4 f0 = *reinterpret_cast<const float4*>(src);
      float4 f1 = *reinterpret_cast<const float4*>(src+4);
      bf16x8 v;
      v[0]=f2b(f0.x); v[1]=f2b(f0.y); v[2]=f2b(f0.z); v[3]=f2b(f0.w);
      v[4]=f2b(f1.x); v[5]=f2b(f1.y); v[6]=f2b(f1.z); v[7]=f2b(f1.w);
      *reinterpret_cast<bf16x8*>(&As[r][kc]) = v;
      *(int4*)&Bs[r][kc] = *(const int4*)&WoT[(nP+r)*512 + kt + kc];
    }
    __syncthreads();
    #pragma unroll
    for(int ks=0; ks<64; ks+=32){
      int ko = ks + 8*(lane>>4);
      bf16x8 a[4], b[4];
      #pragma unroll
      for(int i=0;i<4;i++){
        a[i] = *(const bf16x8*)&As[wm + i*16 + (lane&15)][ko];
        b[i] = *(const bf16x8*)&Bs[wn + i*16 + (lane&15)][ko];
      }
      #pragma unroll
      for(int mi=0;mi<4;mi++)
        #pragma unroll
        for(int ni=0;ni<4;ni++)
          acc[mi][ni] = __builtin_amdgcn_mfma_f32_16x16x32_bf16(a[mi],b[ni],acc[mi][ni],0,0,0);
    }
    __syncthreads();
  }
  int r0 = (lane>>4)*4, c0 = lane&15;
  for(int mi=0;mi<4;mi++) for(int ni=0;ni<4;ni++){
    int row = mP + wm + mi*16 + r0, col = nP + wn + ni*16 + c0;
    #pragma unroll
    for(int r=0;r<4;r++) x2pre[(size_t)(row+r)*512 + col] = f2b(acc[mi][ni][r]);
  }
}

// ---------------- img-branch finish: LN/silu, w_ims, pstoch/pm/ps -----------
__global__ __launch_bounds__(256) void k_imgpost(const short* __restrict__ x2pre,
    const float* __restrict__ og, const float* __restrict__ ob,
    const float* __restrict__ w_ims, const float* __restrict__ b_ims,
    const float* __restrict__ eps_prior, float* __restrict__ out){
  int tid = threadIdx.x;
  int g = tid>>5, l = tid&31;
  int rbase = blockIdx.x*8;
  __shared__ float x2[8][512]; __shared__ float sl[8][64];
  int row = rbase + g;
  float vals[16]; float s=0.f, sq=0.f;
  #pragma unroll
  for(int i=0;i<16;i++){
    int k = l + i*32;
    float v = b2f(x2pre[(size_t)row*512+k]);
    vals[i] = v; s += v; sq += v*v;
  }
  #pragma unroll
  for(int m=1;m<32;m<<=1){ s += __shfl_xor(s, m); sq += __shfl_xor(sq, m); }
  float mu = s/512.f, var = sq/512.f - mu*mu;
  float rstd = rsqrtf(var + 1e-3f);
  #pragma unroll
  for(int i=0;i<16;i++){
    int k = l + i*32;
    float xn = (vals[i]-mu)*rstd*og[k]+ob[k];
    x2[g][k] = xn/(1.f+expf(-xn));
  }
  __syncthreads();
  { int q = tid>>6, n = tid&63;
    float a0=0.f, a1=0.f;
    for(int k=0;k<512;k++){
      float w = w_ims[k*64+n];
      a0 += x2[q][k]*w; a1 += x2[q+4][k]*w;
    }
    sl[q][n]=a0; sl[q+4][n]=a1; }
  __syncthreads();
  { int r = tid>>5, n = tid&31; int rw = rbase + r;
    float pm = sl[r][n] + b_ims[n];
    float psd = softplusf_(sl[r][n+32] + b_ims[n+32]) + 0.1f;
    float ep = eps_prior[(size_t)rw*32+n];
    size_t base = (size_t)rw*704;
    out[base+96+n] = pm + psd*ep; out[base+128+n] = pm; out[base+160+n] = psd; }
}

extern "C" void kernel_launch(void* const* d_in, const int* in_sizes, int n_in,
                              void* d_out, int out_size, void* d_ws, size_t ws_size,
                              hipStream_t stream) {
  const float* embed     = (const float*)d_in[0];
  const float* action    = (const float*)d_in[1];
  const float* is_first  = (const float*)d_in[2];
  const float* eps_prior = (const float*)d_in[3];
  const float* eps_post  = (const float*)d_in[4];
  const float* W_init    = (const float*)d_in[5];
  const float* w_in      = (const float*)d_in[6];
  const float* ln_in_g   = (const float*)d_in[7];
  const float* ln_in_b   = (const float*)d_in[8];
  const float* w_gru     = (const float*)d_in[9];
  const float* ln_gru_g  = (const float*)d_in[10];
  const float* ln_gru_b  = (const float*)d_in[11];
  const float* w_out     = (const float*)d_in[12];
  const float* ln_out_g  = (const float*)d_in[13];
  const float* ln_out_b  = (const float*)d_in[14];
  const float* w_ims     = (const float*)d_in[15];
  const float* b_ims     = (const float*)d_in[16];
  const float* w_obs     = (const float*)d_in[17];
  const float* ln_obs_g  = (const float*)d_in[18];
  const float* ln_obs_b  = (const float*)d_in[19];
  const float* w_ostat   = (const float*)d_in[20];
  const float* b_ostat   = (const float*)d_in[21];
  float* out = (float*)d_out;
  char* ws = (char*)d_ws;

  short* WinT    = (short*)(ws + 0);         //    65,536
  short* WgruT   = (short*)(ws + 65536);     // 3,145,728
  short* WobsT   = (short*)(ws + 3211264);   // 1,572,864
  short* WostatT = (short*)(ws + 4784128);   //    65,536
  short* WoutT   = (short*)(ws + 4849664);   //   524,288
  float* deter0  = (float*)(ws + 5373952);   //     2,048
  float* stoch0  = (float*)(ws + 5376000);   //       256
  short* x2pre   = (short*)(ws + 5376256);   // 33,554,432
  // total ws use ≈ 38.9 MB

  dim3 blk(256);
  hipLaunchKernelGGL(k_wt, dim3(10496), blk, 0, stream,
                     w_in, w_gru, w_obs, w_ostat, w_out,
                     WinT, WgruT, WobsT, WostatT, WoutT);
  hipLaunchKernelGGL(k_init, dim3(1), dim3(512), 0, stream,
                     W_init, w_out, ln_out_g, ln_out_b, w_ims, b_ims, deter0, stoch0);
  hipLaunchKernelGGL(k_scan, dim3(32), dim3(1024), 0, stream,
                     embed, action, is_first, eps_post,
                     WinT, ln_in_g, ln_in_b,
                     WgruT, ln_gru_g, ln_gru_b,
                     WobsT, ln_obs_g, ln_obs_b,
                     WostatT, b_ostat,
                     deter0, stoch0, out);
  hipLaunchKernelGGL(k_img, dim3(256,4), blk, 0, stream, out, WoutT, x2pre);
  hipLaunchKernelGGL(k_imgpost, dim3(4096), blk, 0, stream,
                     x2pre, ln_out_g, ln_out_b, w_ims, b_ims, eps_prior, out);
}

// Round 9
// 6854.002 us; speedup vs baseline: 1.5321x; 1.5321x over previous
//
#include <hip/hip_runtime.h>
#include <hip/hip_bf16.h>

// RSSM scan: B=512, T=64, STOCH=32, DETER=512, HIDDEN=512, ACT=12, EMBED=1024
// out per (b,t): [ostoch32, om32, ostd32, pstoch32, pm32, ps32, deter512] = 704 f32
// Round-9 structure: embed@w_obs precomputed for ALL (b,t) in one GEMM (k_pre)
// -> scan's per-step weight set = 3.64 MB < 4 MB per-XCD L2 -> L2-resident.
// Scan: 32 blocks (4/XCD) x 1024 thr, block owns 16 batch rows for all 64 steps.

typedef __attribute__((ext_vector_type(8))) short bf16x8;
typedef __attribute__((ext_vector_type(4))) float f32x4;

static __device__ __forceinline__ short f2b(float x){
  __hip_bfloat16 h = __float2bfloat16(x);
  return *reinterpret_cast<short*>(&h);
}
static __device__ __forceinline__ float b2f(short s){
  __hip_bfloat16 h = *reinterpret_cast<__hip_bfloat16*>(&s);
  return __bfloat162float(h);
}
static __device__ __forceinline__ float softplusf_(float x){
  return (x > 20.f) ? x : log1pf(expf(x));
}
static __device__ __forceinline__ float sigm(float x){ return 1.f/(1.f+expf(-x)); }

// ---------------- weight convert (one-time): nt-major fragment layouts ------
// value(nt,ks,l,e) = W[k][n], k=ks*32+(l>>4)*8+e, n=nt*16+(l&15)
// linear = ((nt*NKS + ks)*64 + l)*8 + e
__global__ __launch_bounds__(256) void k_wt(
    const float* __restrict__ wi, const float* __restrict__ wg,
    const float* __restrict__ wo, const float* __restrict__ wst,
    const float* __restrict__ wou,
    short* __restrict__ WinT, short* __restrict__ WgruT,
    short* __restrict__ WobsDT, short* __restrict__ WobsE,
    short* __restrict__ WostatT, short* __restrict__ WoutT){
  int i = blockIdx.x*256 + threadIdx.x;
  if(i < 32768){ // w_in: NT=32, NKS=2 (real K=44)
    int e=i&7, l=(i>>3)&63, f=i>>9; int ks=f&1, nt=f>>1;
    int k=ks*32+((l>>4))*8+e, n=nt*16+(l&15);
    WinT[i] = (k<44)? f2b(wi[k*512+n]) : (short)0;
    return;
  }
  i -= 32768;
  if(i < 1572864){ // w_gru: NT=96, NKS=32
    int e=i&7, l=(i>>3)&63, f=i>>9; int ks=f&31, nt=f>>5;
    int k=ks*32+((l>>4))*8+e, n=nt*16+(l&15);
    WgruT[i] = f2b(wg[k*1536+n]);
    return;
  }
  i -= 1572864;
  if(i < 262144){ // w_obs deter half: NT=32, NKS=16 (K=512)
    int e=i&7, l=(i>>3)&63, f=i>>9; int ks=f&15, nt=f>>4;
    int k=ks*32+((l>>4))*8+e, n=nt*16+(l&15);
    WobsDT[i] = f2b(wo[k*512+n]);
    return;
  }
  i -= 262144;
  if(i < 524288){ // w_obs embed half, row-major [n][k] for k_pre
    int n=i>>10, k=i&1023;
    WobsE[i] = f2b(wo[(512+k)*512+n]);
    return;
  }
  i -= 524288;
  if(i < 32768){ // w_ostat: NT=4, NKS=16
    int e=i&7, l=(i>>3)&63, f=i>>9; int ks=f&15, nt=f>>4;
    int k=ks*32+((l>>4))*8+e, n=nt*16+(l&15);
    WostatT[i] = f2b(wst[k*64+n]);
    return;
  }
  i -= 32768;
  { int n=i>>9, k=i&511; WoutT[i] = f2b(wou[k*512+n]); } // w_out row-major [n][k]
}

// ---------------- init: deter0 = tanh(W_init); stoch0 = img_mean(deter0) -----
__global__ __launch_bounds__(512) void k_init(const float* __restrict__ W_init,
    const float* __restrict__ w_out, const float* __restrict__ og, const float* __restrict__ ob,
    const float* __restrict__ w_ims, const float* __restrict__ b_ims,
    float* __restrict__ deter0, float* __restrict__ stoch0){
  __shared__ float d0[512]; __shared__ float red[512]; __shared__ float x2[512];
  int tid = threadIdx.x;
  float d = tanhf(W_init[tid]); d0[tid] = d; deter0[tid] = d; __syncthreads();
  float s = 0.f;
  for(int k=0;k<512;k++) s += d0[k]*w_out[k*512+tid];
  red[tid] = s; __syncthreads();
  for(int ss=256; ss>0; ss>>=1){ if(tid<ss) red[tid]+=red[tid+ss]; __syncthreads(); }
  float sum = red[0]; __syncthreads();
  red[tid] = s*s; __syncthreads();
  for(int ss=256; ss>0; ss>>=1){ if(tid<ss) red[tid]+=red[tid+ss]; __syncthreads(); }
  float sq = red[0];
  float mu = sum/512.f, var = sq/512.f - mu*mu;
  float rstd = rsqrtf(var + 1e-3f);
  float xn = (s-mu)*rstd*og[tid] + ob[tid];
  float xs = xn*sigm(xn);
  x2[tid] = xs; __syncthreads();
  if(tid < 32){
    float acc = b_ims[tid];
    for(int k=0;k<512;k++) acc += x2[k]*w_ims[k*64+tid];
    stoch0[tid] = acc;
  }
}

// ---------------- k_pre: xoE = embed @ w_obs[512:] for all 32768 rows -------
// M=32768, N=512, K=1024; BM=BN=128, BK=64; out bf16
__global__ __launch_bounds__(256) void k_pre(const float* __restrict__ emb,
    const short* __restrict__ WeT, short* __restrict__ xoE){
  __shared__ __align__(16) short As[128][72];
  __shared__ __align__(16) short Bs[128][72];
  int tid = threadIdx.x, lane = tid&63, wid = tid>>6;
  int wm = (wid>>1)*64, wn = (wid&1)*64;
  int mP = blockIdx.x*128, nP = blockIdx.y*128;
  f32x4 acc[4][4] = {};
  for(int kt=0; kt<1024; kt+=64){
    #pragma unroll
    for(int c=0;c<4;c++){
      int idx = tid + c*256; int r = idx>>3, kc = (idx&7)*8;
      const float* src = &emb[(size_t)(mP+r)*1024 + kt + kc];
      float4 f0 = *reinterpret_cast<const float4*>(src);
      float4 f1 = *reinterpret_cast<const float4*>(src+4);
      bf16x8 v;
      v[0]=f2b(f0.x); v[1]=f2b(f0.y); v[2]=f2b(f0.z); v[3]=f2b(f0.w);
      v[4]=f2b(f1.x); v[5]=f2b(f1.y); v[6]=f2b(f1.z); v[7]=f2b(f1.w);
      *reinterpret_cast<bf16x8*>(&As[r][kc]) = v;
      *(int4*)&Bs[r][kc] = *(const int4*)&WeT[(size_t)(nP+r)*1024 + kt + kc];
    }
    __syncthreads();
    #pragma unroll
    for(int ks=0; ks<64; ks+=32){
      int ko = ks + 8*(lane>>4);
      bf16x8 a[4], b[4];
      #pragma unroll
      for(int i=0;i<4;i++){
        a[i] = *(const bf16x8*)&As[wm + i*16 + (lane&15)][ko];
        b[i] = *(const bf16x8*)&Bs[wn + i*16 + (lane&15)][ko];
      }
      #pragma unroll
      for(int mi=0;mi<4;mi++)
        #pragma unroll
        for(int ni=0;ni<4;ni++)
          acc[mi][ni] = __builtin_amdgcn_mfma_f32_16x16x32_bf16(a[mi],b[ni],acc[mi][ni],0,0,0);
    }
    __syncthreads();
  }
  int r0 = (lane>>4)*4, c0 = lane&15;
  for(int mi=0;mi<4;mi++) for(int ni=0;ni<4;ni++){
    int row = mP + wm + mi*16 + r0, col = nP + wn + ni*16 + c0;
    #pragma unroll
    for(int r=0;r<4;r++) xoE[(size_t)(row+r)*512 + col] = f2b(acc[mi][ni][r]);
  }
}

// ---------------- the scan: 32 blocks x 1024 threads ------------------------
__global__ __launch_bounds__(1024) void k_scan(
    const float* __restrict__ action,
    const float* __restrict__ isf, const float* __restrict__ eps_post,
    const short* __restrict__ WinT, const float* __restrict__ ig, const float* __restrict__ ib,
    const short* __restrict__ WgruT, const float* __restrict__ gg, const float* __restrict__ gb,
    const short* __restrict__ WobsDT, const short* __restrict__ xoE,
    const float* __restrict__ og, const float* __restrict__ ob,
    const short* __restrict__ WostatT, const float* __restrict__ b_ostat,
    const float* __restrict__ deter0, const float* __restrict__ stoch0,
    float* __restrict__ out)
{
  __shared__ __align__(16) short RB[16*1032];   // xd bf16[16][1032]
  __shared__ __align__(16) short PB[16*1544];   // parts bf16[16][1544] / xoF f32[16][520]
  __shared__ float deterS[16][516];
  __shared__ short dB[16][520];     // deter_n bf16 (S6 A), then xo bf16 (S8 A)
  __shared__ short xrow[16][72];
  __shared__ float stochS[16][32];
  __shared__ float sol[16][64];
  __shared__ float sumA[16], sqA[16], sumB[16], sqB[16], sumC[16], sqC[16];
  __shared__ float fr[16];
  __shared__ float d0s[512]; __shared__ float s0s[32];

  const int g = blockIdx.x, tid = threadIdx.x;
  const int w = tid>>6, lane = tid&63;
  const int col0 = lane&15, rg4 = (lane>>4)*4;
  const int afo = (lane>>4)*8;
  float* xoF = (float*)PB;

  // ---- init state ----
  if(tid < 512) d0s[tid] = deter0[tid];
  if(tid < 32)  s0s[tid] = stoch0[tid];
  __syncthreads();
  { int r = tid>>6, kb = (tid&63)*8;
    #pragma unroll
    for(int i=0;i<8;i++) deterS[r][kb+i] = d0s[kb+i]; }
  if(tid < 512){ int r=tid>>5, c=tid&31; stochS[r][c] = s0s[c]; }
  __syncthreads();

  for(int t=0; t<64; t++){
    // ---- S0a: is_first + zero LN-stat buffers ----
    if(tid < 16){
      fr[tid] = isf[(g*16+tid)*64 + t];
      sumA[tid]=0.f; sqA[tid]=0.f; sumB[tid]=0.f; sqB[tid]=0.f; sumC[tid]=0.f; sqC[tid]=0.f;
    }
    __syncthreads();
    // ---- S0b: mask stoch/action -> xrow; mask deter -> deterS + xd[512:1024] ----
    if(tid < 512){
      int r = tid>>5, c = tid&31; float f = fr[r];
      float sm = stochS[r][c]*(1.f-f) + s0s[c]*f;
      xrow[r][c] = f2b(sm);
      if(c < 12){
        float av = action[((size_t)(g*16+r)*64+t)*12 + c]*(1.f-f);
        xrow[r][32+c] = f2b(av);
      }
      if(c >= 12) xrow[r][32+c] = 0;
    }
    { int r = tid>>6, kb = (tid&63)*8; float f = fr[r];
      #pragma unroll
      for(int i=0;i<8;i++){
        int k = kb+i;
        float dm = deterS[r][k]*(1.f-f) + d0s[k]*f;
        deterS[r][k] = dm;
        RB[r*1032 + 512 + k] = f2b(dm);
      } }
    __syncthreads();
    // ---- S1: x_pre = xrow @ w_in -> xd[0:512] + statsA ----
    {
      f32x4 acc[2] = {};
      #pragma unroll
      for(int ks=0; ks<2; ks++){
        bf16x8 a = *(const bf16x8*)&xrow[col0][ks*32 + afo];
        #pragma unroll
        for(int j=0;j<2;j++){
          int nt = w*2+j;
          bf16x8 b = *(const bf16x8*)&WinT[((nt*2 + ks)*64 + lane)*8];
          acc[j] = __builtin_amdgcn_mfma_f32_16x16x32_bf16(a,b,acc[j],0,0,0);
        }
      }
      float s[4]={0,0,0,0}, q[4]={0,0,0,0};
      #pragma unroll
      for(int j=0;j<2;j++){
        int col = (w*2+j)*16 + col0;
        #pragma unroll
        for(int r=0;r<4;r++){
          float v = acc[j][r];
          RB[(rg4+r)*1032 + col] = f2b(v);
          s[r]+=v; q[r]+=v*v;
        }
      }
      #pragma unroll
      for(int r=0;r<4;r++){
        #pragma unroll
        for(int m=1;m<16;m<<=1){ s[r]+=__shfl_xor(s[r],m); q[r]+=__shfl_xor(q[r],m); }
      }
      if(col0==0){
        #pragma unroll
        for(int r=0;r<4;r++){ atomicAdd(&sumA[rg4+r], s[r]); atomicAdd(&sqA[rg4+r], q[r]); }
      }
    }
    __syncthreads();
    // ---- S2: LN+silu x in place ----
    {
      int r = tid>>6, kb = tid&63;
      float mu = sumA[r]/512.f, var = sqA[r]/512.f - mu*mu;
      float rstd = rsqrtf(var + 1e-3f);
      #pragma unroll
      for(int i=0;i<8;i++){
        int k = kb + i*64;
        float v = b2f(RB[r*1032 + k]);
        float xn = (v-mu)*rstd*ig[k] + ib[k];
        RB[r*1032 + k] = f2b(xn*sigm(xn));
      }
    }
    __syncthreads();
    // ---- S3: parts = xd @ w_gru (nt-major streams, round-4 proven body) ----
    {
      f32x4 acc[6] = {};
      const short* xdA = &RB[col0*1032 + afo];
      for(int ks=0; ks<32; ks++){
        bf16x8 a = *(const bf16x8*)(xdA + ks*32);
        #pragma unroll
        for(int j=0;j<6;j++){
          bf16x8 b = *(const bf16x8*)&WgruT[((size_t)((w*6+j)*32 + ks)*64 + lane)*8];
          acc[j] = __builtin_amdgcn_mfma_f32_16x16x32_bf16(a,b,acc[j],0,0,0);
        }
      }
      float s[4]={0,0,0,0}, q[4]={0,0,0,0};
      #pragma unroll
      for(int j=0;j<6;j++){
        int col = (w*6+j)*16 + col0;
        #pragma unroll
        for(int r=0;r<4;r++){
          float v = acc[j][r];
          PB[(rg4+r)*1544 + col] = f2b(v);
          s[r]+=v; q[r]+=v*v;
        }
      }
      #pragma unroll
      for(int r=0;r<4;r++){
        #pragma unroll
        for(int m=1;m<16;m<<=1){ s[r]+=__shfl_xor(s[r],m); q[r]+=__shfl_xor(q[r],m); }
      }
      if(col0==0){
        #pragma unroll
        for(int r=0;r<4;r++){ atomicAdd(&sumB[rg4+r], s[r]); atomicAdd(&sqB[rg4+r], q[r]); }
      }
    }
    __syncthreads();
    // ---- S4: gates: LN(1536) + GRU update -> deterS, dB, out ----
    {
      int r = tid>>6, jb = tid&63;
      float mu = sumB[r]/1536.f, var = sqB[r]/1536.f - mu*mu;
      float rstd = rsqrtf(var + 1e-3f);
      size_t obase = (size_t)(g*16+r)*45056 + (size_t)t*704 + 192;
      #pragma unroll
      for(int i=0;i<8;i++){
        int j = jb + i*64;
        float xr = (b2f(PB[r*1544 + j      ])-mu)*rstd*gg[j]      + gb[j];
        float xc = (b2f(PB[r*1544 + 512 + j])-mu)*rstd*gg[512+j]  + gb[512+j];
        float xu = (b2f(PB[r*1544 + 1024+ j])-mu)*rstd*gg[1024+j] + gb[1024+j];
        float rr = sigm(xr);
        float cc = tanhf(rr*xc);
        float uu = sigm(xu-1.f);
        float dp = deterS[r][j];
        float dn = uu*cc + (1.f-uu)*dp;
        deterS[r][j] = dn;
        dB[r][j] = f2b(dn);
        out[obase + j] = dn;
      }
    }
    __syncthreads();
    // ---- S6: xo_pre = deter_n @ w_obs_deter + xoE(precomputed embed part) ----
    {
      f32x4 acc[2];
      #pragma unroll
      for(int j=0;j<2;j++){
        int col = (w*2+j)*16 + col0;
        #pragma unroll
        for(int r=0;r<4;r++)
          acc[j][r] = b2f(xoE[((size_t)(g*16+rg4+r)*64 + t)*512 + col]);
      }
      const short* Wo = WobsDT + (size_t)(w*2)*8192 + (size_t)lane*8; // +j*8192 +ks*512
      for(int ks=0; ks<16; ks++){
        bf16x8 a = *(const bf16x8*)&dB[col0][ks*32 + afo];
        #pragma unroll
        for(int j=0;j<2;j++){
          bf16x8 b = *(const bf16x8*)(Wo + j*8192 + ks*512);
          acc[j] = __builtin_amdgcn_mfma_f32_16x16x32_bf16(a,b,acc[j],0,0,0);
        }
      }
      float s[4]={0,0,0,0}, q[4]={0,0,0,0};
      #pragma unroll
      for(int j=0;j<2;j++){
        int col = (w*2+j)*16 + col0;
        #pragma unroll
        for(int r=0;r<4;r++){
          float v = acc[j][r];
          xoF[(rg4+r)*520 + col] = v;
          s[r]+=v; q[r]+=v*v;
        }
      }
      #pragma unroll
      for(int r=0;r<4;r++){
        #pragma unroll
        for(int m=1;m<16;m<<=1){ s[r]+=__shfl_xor(s[r],m); q[r]+=__shfl_xor(q[r],m); }
      }
      if(col0==0){
        #pragma unroll
        for(int r=0;r<4;r++){ atomicAdd(&sumC[rg4+r], s[r]); atomicAdd(&sqC[rg4+r], q[r]); }
      }
    }
    __syncthreads();
    // ---- S7: LN+silu xo -> dB ----
    {
      int r = tid>>6, kb = tid&63;
      float mu = sumC[r]/512.f, var = sqC[r]/512.f - mu*mu;
      float rstd = rsqrtf(var + 1e-3f);
      #pragma unroll
      for(int i=0;i<8;i++){
        int k = kb + i*64;
        float v = xoF[r*520 + k];
        float xn = (v-mu)*rstd*og[k] + ob[k];
        dB[r][k] = f2b(xn*sigm(xn));
      }
    }
    __syncthreads();
    // ---- S8: so = xo @ w_ostat (waves 0..3) ----
    if(w < 4){
      f32x4 acc = {};
      for(int ks=0; ks<16; ks++){
        bf16x8 a = *(const bf16x8*)&dB[col0][ks*32 + afo];
        bf16x8 b = *(const bf16x8*)&WostatT[((w*16 + ks)*64 + lane)*8];
        acc = __builtin_amdgcn_mfma_f32_16x16x32_bf16(a,b,acc,0,0,0);
      }
      #pragma unroll
      for(int r=0;r<4;r++) sol[rg4+r][w*16+col0] = acc[r];
    }
    __syncthreads();
    // ---- S9: om/ostd/ostoch, write out, update stoch carry ----
    if(tid < 512){
      int r = tid>>5, c = tid&31;
      float om  = sol[r][c]    + b_ostat[c];
      float spi = sol[r][32+c] + b_ostat[32+c];
      float osd = softplusf_(spi) + 0.1f;
      float eo  = eps_post[((size_t)(g*16+r)*64+t)*32 + c];
      float ost = om + osd*eo;
      size_t base = (size_t)(g*16+r)*45056 + (size_t)t*704;
      out[base+c] = ost; out[base+32+c] = om; out[base+64+c] = osd;
      stochS[r][c] = ost;
    }
    __syncthreads();
  }
}

// ---------------- deferred img-branch GEMM: x2pre = deter_all @ w_out --------
__global__ __launch_bounds__(256) void k_img(const float* __restrict__ outp,
    const short* __restrict__ WoT, short* __restrict__ x2pre){
  __shared__ __align__(16) short As[128][72];
  __shared__ __align__(16) short Bs[128][72];
  int tid = threadIdx.x, lane = tid&63, wid = tid>>6;
  int wm = (wid>>1)*64, wn = (wid&1)*64;
  int mP = blockIdx.x*128, nP = blockIdx.y*128;
  f32x4 acc[4][4] = {};
  for(int kt=0; kt<512; kt+=64){
    #pragma unroll
    for(int c=0;c<4;c++){
      int idx = tid + c*256; int r = idx>>3, kc = (idx&7)*8;
      const float* src = &outp[(size_t)(mP+r)*704 + 192 + kt + kc];
      float4 f0 = *reinterpret_cast<const float4*>(src);
      float4 f1 = *reinterpret_cast<const float4*>(src+4);
      bf16x8 v;
      v[0]=f2b(f0.x); v[1]=f2b(f0.y); v[2]=f2b(f0.z); v[3]=f2b(f0.w);
      v[4]=f2b(f1.x); v[5]=f2b(f1.y); v[6]=f2b(f1.z); v[7]=f2b(f1.w);
      *reinterpret_cast<bf16x8*>(&As[r][kc]) = v;
      *(int4*)&Bs[r][kc] = *(const int4*)&WoT[(nP+r)*512 + kt + kc];
    }
    __syncthreads();
    #pragma unroll
    for(int ks=0; ks<64; ks+=32){
      int ko = ks + 8*(lane>>4);
      bf16x8 a[4], b[4];
      #pragma unroll
      for(int i=0;i<4;i++){
        a[i] = *(const bf16x8*)&As[wm + i*16 + (lane&15)][ko];
        b[i] = *(const bf16x8*)&Bs[wn + i*16 + (lane&15)][ko];
      }
      #pragma unroll
      for(int mi=0;mi<4;mi++)
        #pragma unroll
        for(int ni=0;ni<4;ni++)
          acc[mi][ni] = __builtin_amdgcn_mfma_f32_16x16x32_bf16(a[mi],b[ni],acc[mi][ni],0,0,0);
    }
    __syncthreads();
  }
  int r0 = (lane>>4)*4, c0 = lane&15;
  for(int mi=0;mi<4;mi++) for(int ni=0;ni<4;ni++){
    int row = mP + wm + mi*16 + r0, col = nP + wn + ni*16 + c0;
    #pragma unroll
    for(int r=0;r<4;r++) x2pre[(size_t)(row+r)*512 + col] = f2b(acc[mi][ni][r]);
  }
}

// ---------------- img-branch finish: LN/silu, w_ims, pstoch/pm/ps -----------
__global__ __launch_bounds__(256) void k_imgpost(const short* __restrict__ x2pre,
    const float* __restrict__ og, const float* __restrict__ ob,
    const float* __restrict__ w_ims, const float* __restrict__ b_ims,
    const float* __restrict__ eps_prior, float* __restrict__ out){
  int tid = threadIdx.x;
  int g = tid>>5, l = tid&31;
  int rbase = blockIdx.x*8;
  __shared__ float x2[8][512]; __shared__ float sl[8][64];
  int row = rbase + g;
  float vals[16]; float s=0.f, sq=0.f;
  #pragma unroll
  for(int i=0;i<16;i++){
    int k = l + i*32;
    float v = b2f(x2pre[(size_t)row*512+k]);
    vals[i] = v; s += v; sq += v*v;
  }
  #pragma unroll
  for(int m=1;m<32;m<<=1){ s += __shfl_xor(s, m); sq += __shfl_xor(sq, m); }
  float mu = s/512.f, var = sq/512.f - mu*mu;
  float rstd = rsqrtf(var + 1e-3f);
  #pragma unroll
  for(int i=0;i<16;i++){
    int k = l + i*32;
    float xn = (vals[i]-mu)*rstd*og[k]+ob[k];
    x2[g][k] = xn/(1.f+expf(-xn));
  }
  __syncthreads();
  { int q = tid>>6, n = tid&63;
    float a0=0.f, a1=0.f;
    for(int k=0;k<512;k++){
      float w = w_ims[k*64+n];
      a0 += x2[q][k]*w; a1 += x2[q+4][k]*w;
    }
    sl[q][n]=a0; sl[q+4][n]=a1; }
  __syncthreads();
  { int r = tid>>5, n = tid&31; int rw = rbase + r;
    float pm = sl[r][n] + b_ims[n];
    float psd = softplusf_(sl[r][n+32] + b_ims[n+32]) + 0.1f;
    float ep = eps_prior[(size_t)rw*32+n];
    size_t base = (size_t)rw*704;
    out[base+96+n] = pm + psd*ep; out[base+128+n] = pm; out[base+160+n] = psd; }
}

extern "C" void kernel_launch(void* const* d_in, const int* in_sizes, int n_in,
                              void* d_out, int out_size, void* d_ws, size_t ws_size,
                              hipStream_t stream) {
  const float* embed     = (const float*)d_in[0];
  const float* action    = (const float*)d_in[1];
  const float* is_first  = (const float*)d_in[2];
  const float* eps_prior = (const float*)d_in[3];
  const float* eps_post  = (const float*)d_in[4];
  const float* W_init    = (const float*)d_in[5];
  const float* w_in      = (const float*)d_in[6];
  const float* ln_in_g   = (const float*)d_in[7];
  const float* ln_in_b   = (const float*)d_in[8];
  const float* w_gru     = (const float*)d_in[9];
  const float* ln_gru_g  = (const float*)d_in[10];
  const float* ln_gru_b  = (const float*)d_in[11];
  const float* w_out     = (const float*)d_in[12];
  const float* ln_out_g  = (const float*)d_in[13];
  const float* ln_out_b  = (const float*)d_in[14];
  const float* w_ims     = (const float*)d_in[15];
  const float* b_ims     = (const float*)d_in[16];
  const float* w_obs     = (const float*)d_in[17];
  const float* ln_obs_g  = (const float*)d_in[18];
  const float* ln_obs_b  = (const float*)d_in[19];
  const float* w_ostat   = (const float*)d_in[20];
  const float* b_ostat   = (const float*)d_in[21];
  float* out = (float*)d_out;
  char* ws = (char*)d_ws;

  short* WinT    = (short*)(ws + 0);         //    65,536
  short* WgruT   = (short*)(ws + 65536);     // 3,145,728
  short* WobsDT  = (short*)(ws + 3211264);   //   524,288
  short* WobsE   = (short*)(ws + 3735552);   // 1,048,576
  short* WostatT = (short*)(ws + 4784128);   //    65,536
  short* WoutT   = (short*)(ws + 4849664);   //   524,288
  float* deter0  = (float*)(ws + 5373952);   //     2,048
  float* stoch0  = (float*)(ws + 5376000);   //       256
  short* xoE     = (short*)(ws + 5376256);   // 33,554,432 (bf16 32768x512)
  short* x2pre   = (short*)(ws + 5376256);   // aliases xoE (dead after scan)
  // total ws use ≈ 38.9 MB

  dim3 blk(256);
  hipLaunchKernelGGL(k_wt, dim3(10496), blk, 0, stream,
                     w_in, w_gru, w_obs, w_ostat, w_out,
                     WinT, WgruT, WobsDT, WobsE, WostatT, WoutT);
  hipLaunchKernelGGL(k_init, dim3(1), dim3(512), 0, stream,
                     W_init, w_out, ln_out_g, ln_out_b, w_ims, b_ims, deter0, stoch0);
  hipLaunchKernelGGL(k_pre, dim3(256,4), blk, 0, stream, embed, WobsE, xoE);
  hipLaunchKernelGGL(k_scan, dim3(32), dim3(1024), 0, stream,
                     action, is_first, eps_post,
                     WinT, ln_in_g, ln_in_b,
                     WgruT, ln_gru_g, ln_gru_b,
                     WobsDT, xoE, ln_obs_g, ln_obs_b,
                     WostatT, b_ostat,
                     deter0, stoch0, out);
  hipLaunchKernelGGL(k_img, dim3(256,4), blk, 0, stream, out, WoutT, x2pre);
  hipLaunchKernelGGL(k_imgpost, dim3(4096), blk, 0, stream,
                     x2pre, ln_out_g, ln_out_b, w_ims, b_ims, eps_prior, out);
}